// Round 6
// baseline (118.055 us; speedup 1.0000x reference)
//
#include <hip/hip_runtime.h>
#include <math.h>

#define DIM 128
#define HEADS 8
#define HD 16
#define NPOS 8192      // 32*32*8
#define EPS 1e-5f
#define RLN2 1.44269504088896f

// ---- f16 helpers -------------------------------------------------
typedef _Float16 half2_t __attribute__((ext_vector_type(2)));
typedef _Float16 f16x8  __attribute__((ext_vector_type(8)));
typedef float    f32x4  __attribute__((ext_vector_type(4)));

static __device__ __forceinline__ half2_t u2h(unsigned u) {
    half2_t r; __builtin_memcpy(&r, &u, 4); return r;
}
static __device__ __forceinline__ unsigned pkh(float a, float b) {
    half2_t h; h.x = (_Float16)a; h.y = (_Float16)b;
    unsigned u; __builtin_memcpy(&u, &h, 4); return u;
}
static __device__ __forceinline__ float dot2(unsigned k, unsigned q, float acc) {
#if __has_builtin(__builtin_amdgcn_fdot2)
    return __builtin_amdgcn_fdot2(u2h(k), u2h(q), acc, false);
#else
    half2_t kh = u2h(k), qh = u2h(q);
    acc = fmaf((float)kh.x, (float)qh.x, acc);
    return fmaf((float)kh.y, (float)qh.y, acc);
#endif
}
static __device__ __forceinline__ float ex2(float x) {
#if __has_builtin(__builtin_amdgcn_exp2f)
    return __builtin_amdgcn_exp2f(x);
#else
    return exp2f(x);
#endif
}

// ---------------- instance-norm stats + W-transpose ----------------
// blocks 0..255: per-channel stats.  ws: [0,128) mu_x [128,256) rs_x
//                                        [256,384) mu_s [384,512) rs_s
// blocks 256..271: transpose the 4 weight matrices into Wt[co][ci] f16.
__global__ __launch_bounds__(256) void stats_kernel(const float* __restrict__ x,
                                                    const float* __restrict__ skip,
                                                    const float* __restrict__ Wq,
                                                    const float* __restrict__ Wk,
                                                    const float* __restrict__ Wv,
                                                    const float* __restrict__ Wo,
                                                    float* __restrict__ ws,
                                                    unsigned short* __restrict__ Wt) {
    int c = blockIdx.x;
    int t = threadIdx.x;
    if (c >= 256) {
        int c2 = c - 256;
        int m = c2 >> 2, chunk = c2 & 3;
        const float* Wsrc = (m == 0) ? Wq : (m == 1) ? Wk : (m == 2) ? Wv : Wo;
        unsigned short* dst = Wt + (size_t)m * 16384;
        int co = t & 127, half = t >> 7;
        int ci0 = chunk * 32 + half * 16;
        unsigned pk8[8];
        #pragma unroll
        for (int j = 0; j < 8; ++j) {
            float a = Wsrc[(ci0 + 2*j    ) * 128 + co];
            float b = Wsrc[(ci0 + 2*j + 1) * 128 + co];
            pk8[j] = pkh(a, b);
        }
        *(uint4*)(dst + (size_t)co * 128 + ci0)     = *(uint4*)&pk8[0];
        *(uint4*)(dst + (size_t)co * 128 + ci0 + 8) = *(uint4*)&pk8[4];
        return;
    }
    const float* src; int n; float* mu_out; float* rs_out; int ci;
    if (c < DIM) { ci = c; src = x + c * 1024; n = 1024; mu_out = ws; rs_out = ws + DIM; }
    else { ci = c - DIM; src = skip + (size_t)ci * NPOS; n = NPOS; mu_out = ws + 2*DIM; rs_out = ws + 3*DIM; }
    const float4* s4 = (const float4*)src;
    int n4 = n >> 2;
    float s = 0.f, s2 = 0.f;
    for (int i = t; i < n4; i += 256) {
        float4 v = s4[i];
        s += (v.x + v.y) + (v.z + v.w);
        s2 = fmaf(v.x, v.x, fmaf(v.y, v.y, fmaf(v.z, v.z, fmaf(v.w, v.w, s2))));
    }
    #pragma unroll
    for (int off = 32; off > 0; off >>= 1) {
        s  += __shfl_down(s,  off, 64);
        s2 += __shfl_down(s2, off, 64);
    }
    __shared__ float ls[4], ls2[4];
    int wv = t >> 6;
    if ((t & 63) == 0) { ls[wv] = s; ls2[wv] = s2; }
    __syncthreads();
    if (t == 0) {
        float S  = ls[0] + ls[1] + ls[2] + ls[3];
        float S2 = ls2[0] + ls2[1] + ls2[2] + ls2[3];
        float inv_n = 1.f / (float)n;
        float mu  = S * inv_n;
        float var = S2 * inv_n - mu * mu;
        mu_out[ci] = mu;
        rs_out[ci] = rsqrtf(var + EPS);
    }
}

// ---------------- unified MFMA GEMM: C = norm(A) @ W + b ----------------
// Block: 32 pos x 128 co, 256 thr = 4 waves; wave w owns co [w*32,w*32+32).
// A staged f16 [pos][ci] in LDS (8KB), XOR-swizzled ((pos&7)<<4).
// W frags from pre-transposed Wt[co][ci] f16 straight into VGPRs.
// mfma_f32_16x16x32_f16: A-op = Wt rows (M=co), B-op = A rows (N=pos)
// -> D[co][pos].  phase 0 grid: 0..255 k, 256..511 v, 512..543 q (q scale
// folds HD^-0.5 and 1/ln2 for the exp2 softmax).  phase 1: A = f16 ao_h.
__global__ __launch_bounds__(256) void gemm_kernel(int phase,
    const float* __restrict__ x, const float* __restrict__ skip,
    const unsigned* __restrict__ ao_h,
    const unsigned short* __restrict__ Wt_all,
    const float* __restrict__ bq, const float* __restrict__ bk,
    const float* __restrict__ bv, const float* __restrict__ bo,
    const float* __restrict__ ws,
    unsigned* __restrict__ q_out, unsigned* __restrict__ k_out,
    unsigned* __restrict__ v_out, float* __restrict__ out) {
    __shared__ __align__(16) unsigned short A_lds[32 * 128];   // 8 KB
    int bx = blockIdx.x;
    const float* A = nullptr; int lda = 0; const float* mu = nullptr; const float* rs = nullptr;
    const unsigned short* Wt; const float* bias; float scale = 1.f;
    unsigned* opk = nullptr; float* of = nullptr; int n0;
    if (phase == 0) {
        if (bx < 256)      { A = skip; lda = NPOS; mu = ws + 256; rs = ws + 384;
                             Wt = Wt_all + 16384;     bias = bk; opk = k_out; n0 = bx * 32; }
        else if (bx < 512) { A = skip; lda = NPOS; mu = ws + 256; rs = ws + 384;
                             Wt = Wt_all + 2 * 16384; bias = bv; opk = v_out; n0 = (bx - 256) * 32; }
        else               { A = x;    lda = 1024; mu = ws;       rs = ws + 128;
                             Wt = Wt_all;             bias = bq; opk = q_out; n0 = (bx - 512) * 32;
                             scale = 0.25f * RLN2; }
    } else {
        Wt = Wt_all + 3 * 16384; bias = bo; of = out; n0 = bx * 32;
    }
    int t = threadIdx.x;
    int lane = t & 63, w = t >> 6;

    // ---- preload W fragments (global, L2-hot): mt(2) x k4(4) = 8 x b128
    int co_f = w * 32 + (lane & 15);
    int kf   = (lane >> 4) * 8;
    uint4 wf[2][4];
    #pragma unroll
    for (int mt = 0; mt < 2; ++mt)
        #pragma unroll
        for (int k4 = 0; k4 < 4; ++k4)
            wf[mt][k4] = *(const uint4*)(Wt + (size_t)(co_f + mt * 16) * 128 + k4 * 32 + kf);

    // ---- stage A -> LDS f16 [pos][ci] (swizzled)
    if (phase == 0) {
        int pos = t & 31, g = t >> 5;          // g 0..7
        const float* ap = A + n0 + pos;
        float f[16];
        #pragma unroll
        for (int rep = 0; rep < 4; ++rep) {
            int ci0 = g * 4 + rep * 32;
            f[rep*4+0] = ap[(size_t)(ci0    ) * lda];
            f[rep*4+1] = ap[(size_t)(ci0 + 1) * lda];
            f[rep*4+2] = ap[(size_t)(ci0 + 2) * lda];
            f[rep*4+3] = ap[(size_t)(ci0 + 3) * lda];
        }
        #pragma unroll
        for (int rep = 0; rep < 4; ++rep) {
            int ci0 = g * 4 + rep * 32;
            float f0 = (f[rep*4+0] - mu[ci0    ]) * rs[ci0    ];
            float f1 = (f[rep*4+1] - mu[ci0 + 1]) * rs[ci0 + 1];
            float f2 = (f[rep*4+2] - mu[ci0 + 2]) * rs[ci0 + 2];
            float f3 = (f[rep*4+3] - mu[ci0 + 3]) * rs[ci0 + 3];
            int byte = (pos * 256 + ci0 * 2) ^ ((pos & 7) << 4);
            *(uint2*)((char*)A_lds + byte) = make_uint2(pkh(f0, f1), pkh(f2, f3));
        }
    } else {
        // ao_h is already f16 [pos][64 uints]: direct uint4 copies
        for (int i = t; i < 512; i += 256) {
            int pos = i >> 4, j = i & 15;
            uint4 u = *(const uint4*)(ao_h + (size_t)(n0 + pos) * 64 + j * 4);
            int byte = (pos * 256 + j * 16) ^ ((pos & 7) << 4);
            *(uint4*)((char*)A_lds + byte) = u;
        }
    }
    __syncthreads();

    // ---- MFMA: 2 m-tiles x 2 n-tiles x 4 k-steps
    f32x4 acc[2][2];
    #pragma unroll
    for (int mt = 0; mt < 2; ++mt)
        #pragma unroll
        for (int nt = 0; nt < 2; ++nt)
            acc[mt][nt] = (f32x4){0.f, 0.f, 0.f, 0.f};
    #pragma unroll
    for (int k4 = 0; k4 < 4; ++k4) {
        f16x8 af[2];
        #pragma unroll
        for (int nt = 0; nt < 2; ++nt) {
            int pos = nt * 16 + (lane & 15);
            int byte = (pos * 256 + (k4 * 32 + kf) * 2) ^ ((pos & 7) << 4);
            uint4 u = *(const uint4*)((const char*)A_lds + byte);
            __builtin_memcpy(&af[nt], &u, 16);
        }
        #pragma unroll
        for (int mt = 0; mt < 2; ++mt) {
            f16x8 wfr; __builtin_memcpy(&wfr, &wf[mt][k4], 16);
            acc[mt][0] = __builtin_amdgcn_mfma_f32_16x16x32_f16(wfr, af[0], acc[mt][0], 0, 0, 0);
            acc[mt][1] = __builtin_amdgcn_mfma_f32_16x16x32_f16(wfr, af[1], acc[mt][1], 0, 0, 0);
        }
    }

    // ---- epilogue
    int colp  = lane & 15;
    int rquad = (lane >> 4) * 4;
    #pragma unroll
    for (int mt = 0; mt < 2; ++mt) {
        int co = w * 32 + mt * 16 + rquad;
        float4 bv4 = *(const float4*)(bias + co);
        #pragma unroll
        for (int nt = 0; nt < 2; ++nt) {
            int pos = n0 + nt * 16 + colp;
            float v0 = (acc[mt][nt][0] + bv4.x) * scale;
            float v1 = (acc[mt][nt][1] + bv4.y) * scale;
            float v2 = (acc[mt][nt][2] + bv4.z) * scale;
            float v3 = (acc[mt][nt][3] + bv4.w) * scale;
            if (phase == 0) {
                *(uint2*)(opk + (size_t)pos * 64 + (co >> 1)) = make_uint2(pkh(v0, v1), pkh(v2, v3));
            } else {
                of[(size_t)(co    ) * NPOS + pos] = v0;
                of[(size_t)(co + 1) * NPOS + pos] = v1;
                of[(size_t)(co + 2) * NPOS + pos] = v2;
                of[(size_t)(co + 3) * NPOS + pos] = v3;
            }
        }
    }
}

// ---------------- neighborhood attention: quad (w-pair x z-pair) sharing ----
// x is 2x-upsampled in h,w,z -> q rows identical across a (w,z) quad, and the
// quad's windows differ by shifts dw,dz in {0,1}. One thread owns a quad:
// one QK dot + one k/v LDS read serve FOUR (pos,nbr) pairs. Union window
// 5x6x6 = 180 pts, masked per pos; bias indices are bidx-{0,1,9,10}.
// grid 512 = 64 tiles(4x4 h,w) x 8 heads; 256 thr = 32 quads x 8 slots.
// Softmax in exp2 domain (1/ln2 folded into q scale and staged bias).
// NaN-safety (R5 post-mortem): masked union points are zeroed via ternary on
// the QK/exp side, but the PV side uses fmaf(0, v, o) which PROPAGATES NaN if
// v reads an unstaged/OOB LDS slot (union gww or gz can reach 8 at edges,
// spilling past the row and past the array). Since every VALID point provably
// has gww<=7 && gz<=7, clamping the LDS coordinates keeps all reads on
// staged finite data without altering any valid read.
__global__ __launch_bounds__(256, 2) void attn_kernel(const unsigned* __restrict__ qb,
                                                      const unsigned* __restrict__ kb,
                                                      const unsigned* __restrict__ vb,
                                                      const float* __restrict__ rpb,
                                                      unsigned* __restrict__ ao_h) {
    __shared__ uint4 kbf[2 * 544];   // slot = gh*68 + gw*8 + ((gz+gw)&7)
    __shared__ uint4 vbf[2 * 544];
    __shared__ float bias_l[744];

    int blk = blockIdx.x;
    int h    = blk & 7;
    int tile = blk >> 3;
    int h0 = (tile >> 3) * 4;
    int w0 = (tile & 7) * 4;
    int bh0 = min(max(h0 - 2, 0), 24);
    int bw0 = min(max(w0 - 2, 0), 24);
    int t = threadIdx.x;

    // zero the 4-slot pad of each row (both chunk-halves, k and v)
    for (int idx = t; idx < 64; idx += 256) {
        int half = idx & 1;
        int r = idx >> 1;                // 0..31
        int row = r >> 2, cpad = r & 3;  // 8 rows x 4 pad slots
        int off = half * 544 + row * 68 + 64 + cpad;
        kbf[off] = make_uint4(0u, 0u, 0u, 0u);
        vbf[off] = make_uint4(0u, 0u, 0u, 0u);
    }
    for (int idx = t; idx < 1024; idx += 256) {
        int c2 = idx & 1;
        int r  = idx >> 1;
        int gz = r & 7;
        int q2 = r >> 3;
        int gh = q2 >> 3, gw = q2 & 7;
        int n = (bh0 + gh) * 256 + (bw0 + gw) * 8 + gz;
        int base = gh * 68 + gw * 8 + ((gz + gw) & 7);
        kbf[c2 * 544 + base] = *(const uint4*)(kb + (size_t)n * 64 + h * 8 + c2 * 4);
        vbf[c2 * 544 + base] = *(const uint4*)(vb + (size_t)n * 64 + h * 8 + c2 * 4);
    }
    for (int idx = t; idx < 744; idx += 256)
        bias_l[idx] = (idx < 729) ? rpb[h * 729 + idx] * RLN2 : 0.f;
    __syncthreads();

    int s = t & 7, p = t >> 3;           // 8 slots x 32 quads
    int ph = p >> 3, pw2 = (p >> 2) & 1, pz2 = p & 3;
    int hc  = h0 + ph;
    int wc0 = w0 + pw2 * 2;              // quad covers w in {wc0, wc0+1}
    int zc0 = pz2 * 2;                   //              z in {zc0, zc0+1}
    int sh  = min(max(hc - 2, 0), 27);
    int sw0 = min(max(wc0 - 2, 0), 27);
    int sw1 = min(max(wc0 - 1, 0), 27);
    int dw  = sw1 - sw0;                 // 0 or 1
    int sz0 = min(max(zc0 - 2, 0), 3);
    int sz1 = min(max(zc0 - 1, 0), 3);
    int dz  = sz1 - sz0;                 // 0 or 1
    int hb = sh - bh0, wb = sw0 - bw0;
    int b0 = (sh - hc + 4) * 81 + (sw0 - wc0 + 4) * 9 + (sz0 - zc0 + 4);
    int n00 = hc * 256 + wc0 * 8 + zc0;

    // shared q (identical across the quad), f16-packed: 8 ch-pairs
    int qrow = (hc >> 1) * 64 + (wc0 >> 1) * 4 + pz2;
    uint4 qa = *(const uint4*)(qb + (size_t)qrow * 64 + h * 8);
    uint4 qc = *(const uint4*)(qb + (size_t)qrow * 64 + h * 8 + 4);

    float o[4][16];                      // [psel*2+zsel][dim]
    float l[4];
    #pragma unroll
    for (int qq = 0; qq < 4; ++qq) {
        l[qq] = 0.f;
        #pragma unroll
        for (int d = 0; d < 16; ++d) o[qq][d] = 0.f;
    }

    // slot partition of the 180 union points: s<4 -> 23, else 22
    int cnt   = 22 + (s < 4);
    int start = s * 22 + min(s, 4);
    int i0 = p & 15;                     // stagger (< 22 always)

    for (int it = 0; it < cnt; ++it) {
        int ii = i0 + it; if (ii >= cnt) ii -= cnt;
        int j = start + ii;              // 0..179
        int jh = (j * 1821) >> 16;       // j / 36
        int jr = j - jh * 36;
        int jw = (jr * 43) >> 8;         // jr / 6
        int jz = jr - jw * 6;            // 0..5
        int gww = wb + jw;
        int gz  = sz0 + jz;
        // clamp to staged region: valid points always have gww<=7 && gz<=7,
        // masked points just need SOME finite staged data (x0 contribution)
        int gwc = min(gww, 7);
        int gzc = min(gz, 7);
        int base = (hb + jh) * 68 + gwc * 8 + ((gzc + gwc) & 7);
        int bidx = b0 + jh * 81 + jw * 9 + jz;
        float b11 = bias_l[bidx - 10];
        float b10 = bias_l[bidx - 9];
        float b01 = bias_l[bidx - 1];
        float b00 = bias_l[bidx];

        uint4 ka = kbf[base];
        uint4 k2 = kbf[544 + base];
        float d0 = dot2(ka.x, qa.x, 0.f);
        float d1 = dot2(ka.y, qa.y, 0.f);
        d0 = dot2(ka.z, qa.z, d0);
        d1 = dot2(ka.w, qa.w, d1);
        d0 = dot2(k2.x, qc.x, d0);
        d1 = dot2(k2.y, qc.y, d1);
        d0 = dot2(k2.z, qc.z, d0);
        d1 = dot2(k2.w, qc.w, d1);
        float d = d0 + d1;               // shared by all 4 positions

        bool vw0 = (jw < 5);
        bool vw1 = ((unsigned)(jw - dw) < 5u);
        bool vz0 = (jz < 5);
        bool vz1 = ((unsigned)(jz - dz) < 5u);
        float p00 = (vw0 && vz0) ? ex2(d + b00) : 0.f;
        float p01 = (vw0 && vz1) ? ex2(d + b01) : 0.f;
        float p10 = (vw1 && vz0) ? ex2(d + b10) : 0.f;
        float p11 = (vw1 && vz1) ? ex2(d + b11) : 0.f;
        l[0] += p00; l[1] += p01; l[2] += p10; l[3] += p11;

        uint4 va = vbf[base];
        uint4 v2 = vbf[544 + base];
        #define PV(u, dd) { half2_t vh = u2h(u); float f0 = (float)vh.x, f1 = (float)vh.y; \
            o[0][dd] = fmaf(p00, f0, o[0][dd]); o[0][dd+1] = fmaf(p00, f1, o[0][dd+1]); \
            o[1][dd] = fmaf(p01, f0, o[1][dd]); o[1][dd+1] = fmaf(p01, f1, o[1][dd+1]); \
            o[2][dd] = fmaf(p10, f0, o[2][dd]); o[2][dd+1] = fmaf(p10, f1, o[2][dd+1]); \
            o[3][dd] = fmaf(p11, f0, o[3][dd]); o[3][dd+1] = fmaf(p11, f1, o[3][dd+1]); }
        PV(va.x, 0)  PV(va.y, 2)  PV(va.z, 4)  PV(va.w, 6)
        PV(v2.x, 8)  PV(v2.y, 10) PV(v2.z, 12) PV(v2.w, 14)
        #undef PV
    }

    // merge 8 slots (lane bits 0..2)
    #pragma unroll
    for (int step = 1; step <= 4; step <<= 1) {
        #pragma unroll
        for (int qq = 0; qq < 4; ++qq) {
            l[qq] += __shfl_xor(l[qq], step, 64);
            #pragma unroll
            for (int d = 0; d < 16; ++d) o[qq][d] += __shfl_xor(o[qq][d], step, 64);
        }
    }
    // lane s stores f16-packed dims (2s,2s+1) for the 4 positions
    int ci = h * 8 + s;
    #pragma unroll
    for (int qq = 0; qq < 4; ++qq) {
        float inv = 1.f / l[qq];
        int pos = n00 + (qq >> 1) * 8 + (qq & 1);
        ao_h[(size_t)pos * 64 + ci] = pkh(o[qq][2*s] * inv, o[qq][2*s+1] * inv);
    }
}

extern "C" void kernel_launch(void* const* d_in, const int* in_sizes, int n_in,
                              void* d_out, int out_size, void* d_ws, size_t ws_size,
                              hipStream_t stream) {
    const float* x    = (const float*)d_in[0];
    const float* skip = (const float*)d_in[1];
    const float* Wq   = (const float*)d_in[2];
    const float* bq   = (const float*)d_in[3];
    const float* Wk   = (const float*)d_in[4];
    const float* bk   = (const float*)d_in[5];
    const float* Wv   = (const float*)d_in[6];
    const float* bv   = (const float*)d_in[7];
    const float* rpb  = (const float*)d_in[8];
    const float* Wo   = (const float*)d_in[9];
    const float* bo   = (const float*)d_in[10];
    float* out = (float*)d_out;

    float*          ws  = (float*)d_ws;
    unsigned short* Wt  = (unsigned short*)(ws + 512);      // 4*16384 f16 = 128 KB
    unsigned* q    = (unsigned*)(Wt + 4 * 16384);           // 1024*64 uints (f16x2)
    unsigned* kbp  = q + 1024 * 64;                         // 8192*64 packed f16
    unsigned* vbp  = kbp + (size_t)NPOS * 64;
    unsigned* ao_h = vbp + (size_t)NPOS * 64;               // 8192*64 packed f16

    stats_kernel<<<272, 256, 0, stream>>>(x, skip, Wq, Wk, Wv, Wo, ws, Wt);
    gemm_kernel<<<544, 256, 0, stream>>>(0, x, skip, ao_h, Wt, bq, bk, bv, bo, ws,
                                         q, kbp, vbp, out);
    attn_kernel<<<512, 256, 0, stream>>>(q, kbp, vbp, rpb, ao_h);
    gemm_kernel<<<256, 256, 0, stream>>>(1, x, skip, ao_h, Wt, bq, bk, bv, bo, ws,
                                         q, kbp, vbp, out);
}